// Round 3
// baseline (123.758 us; speedup 1.0000x reference)
//
#include <hip/hip_runtime.h>
#include <stdint.h>

// (B,T,D)=(32,512,512), M=4096, N_FALSE_NEG=64, TEMP=0.1
#define T_DIM 512
#define D_DIM 512
#define M_ROWS 4096
#define NNEG 64
#define INV_TEMP 10.0f
#define SPAN 4094u        // maxval - minval = (M-2) - 0
#define MULT 1024u        // (2^16 % 4094)^2 % 4094

typedef short v8s __attribute__((ext_vector_type(8)));   // 8 bf16 (4 VGPR)
typedef float v4f __attribute__((ext_vector_type(4)));   // MFMA C/D frag

struct U2 { uint32_t a, b; };

__host__ __device__ constexpr uint32_t rotl32(uint32_t x, uint32_t r) {
  return (x << r) | (x >> (32u - r));
}

// JAX threefry2x32 (20 rounds) — bit-exact vs reference (round 1 absmax 0.0)
__host__ __device__ constexpr U2 tf2x32(uint32_t k0, uint32_t k1,
                                        uint32_t c0, uint32_t c1) {
  uint32_t ks0 = k0, ks1 = k1, ks2 = k0 ^ k1 ^ 0x1BD11BDAu;
  uint32_t x0 = c0 + ks0, x1 = c1 + ks1;
  x0 += x1; x1 = rotl32(x1, 13); x1 ^= x0;
  x0 += x1; x1 = rotl32(x1, 15); x1 ^= x0;
  x0 += x1; x1 = rotl32(x1, 26); x1 ^= x0;
  x0 += x1; x1 = rotl32(x1, 6);  x1 ^= x0;
  x0 += ks1; x1 += ks2 + 1u;
  x0 += x1; x1 = rotl32(x1, 17); x1 ^= x0;
  x0 += x1; x1 = rotl32(x1, 29); x1 ^= x0;
  x0 += x1; x1 = rotl32(x1, 16); x1 ^= x0;
  x0 += x1; x1 = rotl32(x1, 24); x1 ^= x0;
  x0 += ks2; x1 += ks0 + 2u;
  x0 += x1; x1 = rotl32(x1, 13); x1 ^= x0;
  x0 += x1; x1 = rotl32(x1, 15); x1 ^= x0;
  x0 += x1; x1 = rotl32(x1, 26); x1 ^= x0;
  x0 += x1; x1 = rotl32(x1, 6);  x1 ^= x0;
  x0 += ks0; x1 += ks1 + 3u;
  x0 += x1; x1 = rotl32(x1, 17); x1 ^= x0;
  x0 += x1; x1 = rotl32(x1, 29); x1 ^= x0;
  x0 += x1; x1 = rotl32(x1, 16); x1 ^= x0;
  x0 += x1; x1 = rotl32(x1, 24); x1 ^= x0;
  x0 += ks1; x1 += ks2 + 4u;
  x0 += x1; x1 = rotl32(x1, 13); x1 ^= x0;
  x0 += x1; x1 = rotl32(x1, 15); x1 ^= x0;
  x0 += x1; x1 = rotl32(x1, 26); x1 ^= x0;
  x0 += x1; x1 = rotl32(x1, 6);  x1 ^= x0;
  x0 += ks2; x1 += ks0 + 5u;
  return U2{x0, x1};
}

constexpr U2 KHI = tf2x32(0u, 42u, 0u, 0u);  // split(key(42))[0]
constexpr U2 KLO = tf2x32(0u, 42u, 0u, 1u);  // split(key(42))[1]

__device__ inline uint32_t sel_index(uint32_t m, uint32_t j) {
  uint32_t pos = m * 64u + j;
  U2 h = tf2x32(KHI.a, KHI.b, 0u, pos);
  U2 l = tf2x32(KLO.a, KLO.b, 0u, pos);
  uint32_t hi = h.a ^ h.b;
  uint32_t lo = l.a ^ l.b;
  uint32_t r = ((hi % SPAN) * MULT + (lo % SPAN)) % SPAN;
  return r + (r >= m ? 1u : 0u);
}

__device__ inline uint32_t pack_bf2(float lo, float hi) {  // RNE both halves
  uint32_t ul = __float_as_uint(lo); ul += 0x7fffu + ((ul >> 16) & 1u);
  uint32_t uh = __float_as_uint(hi); uh += 0x7fffu + ((uh >> 16) & 1u);
  return (ul >> 16) | (uh & 0xffff0000u);
}
__device__ inline float bflo(int v) { return __uint_as_float(((uint32_t)v) << 16); }
__device__ inline float bfhi(int v) { return __uint_as_float(((uint32_t)v) & 0xffff0000u); }

// Kernel 1: build bf16 normalized-enc table only. 1 wave per row.
__global__ __launch_bounds__(256) void k_norm_enc(
    const float* __restrict__ enc, const int* __restrict__ ids,
    int4* __restrict__ nenc) {
  int lane = threadIdx.x & 63;
  int wave = threadIdx.x >> 6;
  int m = blockIdx.x * 4 + wave;

  int2 rc = ((const int2*)ids)[m];
  size_t base = ((size_t)rc.x * T_DIM + rc.y) * D_DIM;
  const float4* ep = (const float4*)(enc + base);
  float4 e0 = ep[2 * lane], e1 = ep[2 * lane + 1];

  float se = e0.x*e0.x + e0.y*e0.y + e0.z*e0.z + e0.w*e0.w
           + e1.x*e1.x + e1.y*e1.y + e1.z*e1.z + e1.w*e1.w;
  #pragma unroll
  for (int off = 1; off < 64; off <<= 1) se += __shfl_xor(se, off, 64);
  float inv_e = 1.0f / fmaxf(sqrtf(se), 1e-12f);

  int4 eq;
  eq.x = pack_bf2(e0.x * inv_e, e0.y * inv_e);
  eq.y = pack_bf2(e0.z * inv_e, e0.w * inv_e);
  eq.z = pack_bf2(e1.x * inv_e, e1.y * inv_e);
  eq.w = pack_bf2(e1.z * inv_e, e1.w * inv_e);
  nenc[m * 64 + lane] = eq;
}

// Kernel 2: 1 wave per row. Own p-row gather+norm+sim0, then 64 negative
// dots via MFMA: A = 16 gathered candidate rows (measured layout
// A[m=lane&15][k=quad*8+j]), B = p-chunk replicated over n.
__global__ __launch_bounds__(256) void k_contrast(
    const float* __restrict__ pred, const int* __restrict__ ids,
    const int4* __restrict__ nenc, float2* __restrict__ partials) {
  int lane = threadIdx.x & 63;
  int wave = threadIdx.x >> 6;
  int m = blockIdx.x * 4 + wave;
  int col = lane & 15;
  int quad = lane >> 4;

  __shared__ int sel_lds[4][64];
  __shared__ int4 p_lds[4][64];      // bf16 p row per wave (1 KB each)
  __shared__ float2 wred[4];

  // --- own p row: gather fp32, normalize ---
  int2 rc = ((const int2*)ids)[m];
  size_t base = ((size_t)rc.x * T_DIM + rc.y) * D_DIM;
  const float4* pp = (const float4*)(pred + base);
  float4 p0 = pp[2 * lane], p1 = pp[2 * lane + 1];
  float sp = p0.x*p0.x + p0.y*p0.y + p0.z*p0.z + p0.w*p0.w
           + p1.x*p1.x + p1.y*p1.y + p1.z*p1.z + p1.w*p1.w;
  #pragma unroll
  for (int off = 1; off < 64; off <<= 1) sp += __shfl_xor(sp, off, 64);
  float inv_p = 1.0f / fmaxf(sqrtf(sp), 1e-12f);
  float pn0 = p0.x*inv_p, pn1 = p0.y*inv_p, pn2 = p0.z*inv_p, pn3 = p0.w*inv_p;
  float pn4 = p1.x*inv_p, pn5 = p1.y*inv_p, pn6 = p1.z*inv_p, pn7 = p1.w*inv_p;

  int4 pq;
  pq.x = pack_bf2(pn0, pn1); pq.y = pack_bf2(pn2, pn3);
  pq.z = pack_bf2(pn4, pn5); pq.w = pack_bf2(pn6, pn7);
  p_lds[wave][lane] = pq;                       // lane-owned; same-wave reads
  sel_lds[wave][lane] = (int)sel_index((uint32_t)m, (uint32_t)lane);

  // --- sim0 = dot(p_norm, own nenc row) ---
  int4 eq = nenc[m * 64 + lane];
  float dp = pn0 * bflo(eq.x);
  dp = fmaf(pn1, bfhi(eq.x), dp);
  dp = fmaf(pn2, bflo(eq.y), dp);
  dp = fmaf(pn3, bfhi(eq.y), dp);
  dp = fmaf(pn4, bflo(eq.z), dp);
  dp = fmaf(pn5, bfhi(eq.z), dp);
  dp = fmaf(pn6, bflo(eq.w), dp);
  dp = fmaf(pn7, bfhi(eq.w), dp);
  #pragma unroll
  for (int off = 1; off < 64; off <<= 1) dp += __shfl_xor(dp, off, 64);
  float s0 = dp * INV_TEMP;

  // --- candidate row base pointers (stable across k-steps) ---
  const int4* aptr[4];
  #pragma unroll
  for (int c = 0; c < 4; ++c) {
    int sel = sel_lds[wave][16 * c + col];       // 16-word stride-1: conflict-free
    aptr[c] = nenc + (size_t)sel * 64;
  }

  v4f acc0 = {0,0,0,0}, acc1 = {0,0,0,0}, acc2 = {0,0,0,0}, acc3 = {0,0,0,0};
  const char* pbase = (const char*)&p_lds[wave][0];

  #pragma unroll 4
  for (int t = 0; t < 16; ++t) {
    v8s b = *(const v8s*)(pbase + 64 * t + 16 * quad);  // 4-addr broadcast
    int idx = 4 * t + quad;
    union { int4 i; v8s s; } a0, a1, a2, a3;
    a0.i = aptr[0][idx]; a1.i = aptr[1][idx];
    a2.i = aptr[2][idx]; a3.i = aptr[3][idx];
    acc0 = __builtin_amdgcn_mfma_f32_16x16x32_bf16(a0.s, b, acc0, 0, 0, 0);
    acc1 = __builtin_amdgcn_mfma_f32_16x16x32_bf16(a1.s, b, acc1, 0, 0, 0);
    acc2 = __builtin_amdgcn_mfma_f32_16x16x32_bf16(a2.s, b, acc2, 0, 0, 0);
    acc3 = __builtin_amdgcn_mfma_f32_16x16x32_bf16(a3.s, b, acc3, 0, 0, 0);
  }

  // D[row][col]: row = candidate-in-tile = quad*4+reg (col replicated).
  // Lane covers candidates {16c + quad*4 + reg}: 16 of 64; quads partition.
  float se = 0.0f, maxneg = -1e30f;
  #pragma unroll
  for (int r = 0; r < 4; ++r) {
    float s_0 = acc0[r] * INV_TEMP, s_1 = acc1[r] * INV_TEMP;
    float s_2 = acc2[r] * INV_TEMP, s_3 = acc3[r] * INV_TEMP;
    maxneg = fmaxf(fmaxf(fmaxf(maxneg, s_0), fmaxf(s_1, s_2)), s_3);
    se += __expf(s_0) + __expf(s_1) + __expf(s_2) + __expf(s_3);
  }
  // sum/max across the 4 quads (lanes within a quad hold identical partials)
  se += __shfl_xor(se, 16, 64);
  se += __shfl_xor(se, 32, 64);
  maxneg = fmaxf(maxneg, __shfl_xor(maxneg, 16, 64));
  maxneg = fmaxf(maxneg, __shfl_xor(maxneg, 32, 64));

  if (lane == 0) {
    float lse = logf(se + __expf(s0));
    wred[wave] = make_float2(lse - s0, (s0 >= maxneg) ? 1.0f : 0.0f);
  }
  __syncthreads();
  if (threadIdx.x == 0) {
    float l = 0.0f, a = 0.0f;
    #pragma unroll
    for (int w = 0; w < 4; ++w) { l += wred[w].x; a += wred[w].y; }
    partials[blockIdx.x] = make_float2(l, a);
  }
}

// Kernel 3: reduce 1024 block partials -> (loss, acc)
__global__ __launch_bounds__(256) void k_finalize(
    const float2* __restrict__ partials, float* __restrict__ out) {
  int t = threadIdx.x;
  float l = 0.0f, a = 0.0f;
  #pragma unroll
  for (int i = 0; i < 4; ++i) {
    float2 v = partials[t + 256 * i];
    l += v.x; a += v.y;
  }
  #pragma unroll
  for (int off = 1; off < 64; off <<= 1) {
    l += __shfl_xor(l, off, 64);
    a += __shfl_xor(a, off, 64);
  }
  __shared__ float2 wred[4];
  if ((t & 63) == 0) wred[t >> 6] = make_float2(l, a);
  __syncthreads();
  if (t == 0) {
    out[0] = (wred[0].x + wred[1].x + wred[2].x + wred[3].x) * (1.0f / M_ROWS);
    out[1] = (wred[0].y + wred[1].y + wred[2].y + wred[3].y) * (1.0f / M_ROWS);
  }
}

extern "C" void kernel_launch(void* const* d_in, const int* in_sizes, int n_in,
                              void* d_out, int out_size, void* d_ws, size_t ws_size,
                              hipStream_t stream) {
  const float* pred = (const float*)d_in[0];
  const float* enc  = (const float*)d_in[1];
  const int*   ids  = (const int*)d_in[2];
  float* out = (float*)d_out;

  // ws: nenc bf16 table (4 MB) | partials (1024 float2)
  int4* nenc = (int4*)d_ws;
  float2* partials = (float2*)(nenc + (size_t)M_ROWS * 64);

  k_norm_enc<<<M_ROWS / 4, 256, 0, stream>>>(enc, ids, nenc);
  k_contrast<<<M_ROWS / 4, 256, 0, stream>>>(pred, ids, nenc, partials);
  k_finalize<<<1, 256, 0, stream>>>(partials, out);
}

// Round 4
// 115.113 us; speedup vs baseline: 1.0751x; 1.0751x over previous
//
#include <hip/hip_runtime.h>
#include <stdint.h>

// (B,T,D)=(32,512,512), M=4096, N_FALSE_NEG=64, TEMP=0.1
#define T_DIM 512
#define D_DIM 512
#define M_ROWS 4096
#define NNEG 64
#define INV_TEMP 10.0f
#define SPAN 4094u        // maxval - minval = (M-2) - 0
#define MULT 1024u        // (2^16 % 4094)^2 % 4094

typedef float v2f __attribute__((ext_vector_type(2)));

struct U2 { uint32_t a, b; };

__host__ __device__ constexpr uint32_t rotl32(uint32_t x, uint32_t r) {
  return (x << r) | (x >> (32u - r));
}

// JAX threefry2x32 (20 rounds) — bit-exact vs reference (round 1 absmax 0.0)
__host__ __device__ constexpr U2 tf2x32(uint32_t k0, uint32_t k1,
                                        uint32_t c0, uint32_t c1) {
  uint32_t ks0 = k0, ks1 = k1, ks2 = k0 ^ k1 ^ 0x1BD11BDAu;
  uint32_t x0 = c0 + ks0, x1 = c1 + ks1;
  x0 += x1; x1 = rotl32(x1, 13); x1 ^= x0;
  x0 += x1; x1 = rotl32(x1, 15); x1 ^= x0;
  x0 += x1; x1 = rotl32(x1, 26); x1 ^= x0;
  x0 += x1; x1 = rotl32(x1, 6);  x1 ^= x0;
  x0 += ks1; x1 += ks2 + 1u;
  x0 += x1; x1 = rotl32(x1, 17); x1 ^= x0;
  x0 += x1; x1 = rotl32(x1, 29); x1 ^= x0;
  x0 += x1; x1 = rotl32(x1, 16); x1 ^= x0;
  x0 += x1; x1 = rotl32(x1, 24); x1 ^= x0;
  x0 += ks2; x1 += ks0 + 2u;
  x0 += x1; x1 = rotl32(x1, 13); x1 ^= x0;
  x0 += x1; x1 = rotl32(x1, 15); x1 ^= x0;
  x0 += x1; x1 = rotl32(x1, 26); x1 ^= x0;
  x0 += x1; x1 = rotl32(x1, 6);  x1 ^= x0;
  x0 += ks0; x1 += ks1 + 3u;
  x0 += x1; x1 = rotl32(x1, 17); x1 ^= x0;
  x0 += x1; x1 = rotl32(x1, 29); x1 ^= x0;
  x0 += x1; x1 = rotl32(x1, 16); x1 ^= x0;
  x0 += x1; x1 = rotl32(x1, 24); x1 ^= x0;
  x0 += ks1; x1 += ks2 + 4u;
  x0 += x1; x1 = rotl32(x1, 13); x1 ^= x0;
  x0 += x1; x1 = rotl32(x1, 15); x1 ^= x0;
  x0 += x1; x1 = rotl32(x1, 26); x1 ^= x0;
  x0 += x1; x1 = rotl32(x1, 6);  x1 ^= x0;
  x0 += ks2; x1 += ks0 + 5u;
  return U2{x0, x1};
}

constexpr U2 KHI = tf2x32(0u, 42u, 0u, 0u);  // split(key(42))[0]
constexpr U2 KLO = tf2x32(0u, 42u, 0u, 1u);  // split(key(42))[1]

__device__ inline uint32_t sel_index(uint32_t m, uint32_t j) {
  uint32_t pos = m * 64u + j;
  U2 h = tf2x32(KHI.a, KHI.b, 0u, pos);
  U2 l = tf2x32(KLO.a, KLO.b, 0u, pos);
  uint32_t hi = h.a ^ h.b;
  uint32_t lo = l.a ^ l.b;
  uint32_t r = ((hi % SPAN) * MULT + (lo % SPAN)) % SPAN;
  return r + (r >= m ? 1u : 0u);
}

// Kernel 1: build fp8-e4m3 normalized-enc table (512 B/row). 1 wave per row.
__global__ __launch_bounds__(256) void k_norm_enc(
    const float* __restrict__ enc, const int* __restrict__ ids,
    int2* __restrict__ nenc) {
  int lane = threadIdx.x & 63;
  int wave = threadIdx.x >> 6;
  int m = blockIdx.x * 4 + wave;

  int2 rc = ((const int2*)ids)[m];
  size_t base = ((size_t)rc.x * T_DIM + rc.y) * D_DIM;
  const float4* ep = (const float4*)(enc + base);
  float4 e0 = ep[2 * lane], e1 = ep[2 * lane + 1];

  float se = e0.x*e0.x + e0.y*e0.y + e0.z*e0.z + e0.w*e0.w
           + e1.x*e1.x + e1.y*e1.y + e1.z*e1.z + e1.w*e1.w;
  #pragma unroll
  for (int off = 1; off < 64; off <<= 1) se += __shfl_xor(se, off, 64);
  float inv_e = 1.0f / fmaxf(sqrtf(se), 1e-12f);

  // HW fp8 pack (OCP e4m3 on gfx950); decode uses the matching HW cvt, so
  // the pair is self-consistent.
  int w0 = __builtin_amdgcn_cvt_pk_fp8_f32(e0.x * inv_e, e0.y * inv_e, 0, false);
  w0     = __builtin_amdgcn_cvt_pk_fp8_f32(e0.z * inv_e, e0.w * inv_e, w0, true);
  int w1 = __builtin_amdgcn_cvt_pk_fp8_f32(e1.x * inv_e, e1.y * inv_e, 0, false);
  w1     = __builtin_amdgcn_cvt_pk_fp8_f32(e1.z * inv_e, e1.w * inv_e, w1, true);
  nenc[m * 64 + lane] = make_int2(w0, w1);
}

// 8-elem fp8 dot against 8 fp32 weights (4 cvt + 8 fma)
__device__ inline float dot8_fp8(int2 q, const float* pn) {
  v2f a = __builtin_amdgcn_cvt_pk_f32_fp8(q.x, false);
  float d = pn[0] * a.x;
  d = fmaf(pn[1], a.y, d);
  a = __builtin_amdgcn_cvt_pk_f32_fp8(q.x, true);
  d = fmaf(pn[2], a.x, d); d = fmaf(pn[3], a.y, d);
  a = __builtin_amdgcn_cvt_pk_f32_fp8(q.y, false);
  d = fmaf(pn[4], a.x, d); d = fmaf(pn[5], a.y, d);
  a = __builtin_amdgcn_cvt_pk_f32_fp8(q.y, true);
  d = fmaf(pn[6], a.x, d); d = fmaf(pn[7], a.y, d);
  return d;
}

// Kernel 2: 1 wave per row. Gather+norm own p row (fp32, coalesced), sim0
// vs own fp8 row, then 64 negatives: coalesced 512B row loads, VALU dot,
// 4 interleaved butterflies, unshifted exp (|sim|<=10 is fp32-safe).
__global__ __launch_bounds__(256) void k_contrast(
    const float* __restrict__ pred, const int* __restrict__ ids,
    const int2* __restrict__ nenc, float2* __restrict__ partials) {
  int lane = threadIdx.x & 63;
  int wave = threadIdx.x >> 6;
  int m = blockIdx.x * 4 + wave;

  __shared__ int sel_lds[4][64];
  __shared__ float2 wred[4];
  sel_lds[wave][lane] = (int)sel_index((uint32_t)m, (uint32_t)lane);

  // own p row: fp32 gather (wave-coalesced 2KB), normalize in-register
  int2 rc = ((const int2*)ids)[m];
  size_t base = ((size_t)rc.x * T_DIM + rc.y) * D_DIM;
  const float4* pp = (const float4*)(pred + base);
  float4 p0 = pp[2 * lane], p1 = pp[2 * lane + 1];
  float sp = p0.x*p0.x + p0.y*p0.y + p0.z*p0.z + p0.w*p0.w
           + p1.x*p1.x + p1.y*p1.y + p1.z*p1.z + p1.w*p1.w;
  #pragma unroll
  for (int off = 1; off < 64; off <<= 1) sp += __shfl_xor(sp, off, 64);
  float inv_p = 1.0f / fmaxf(sqrtf(sp), 1e-12f);

  float pn[8];
  pn[0] = p0.x*inv_p; pn[1] = p0.y*inv_p; pn[2] = p0.z*inv_p; pn[3] = p0.w*inv_p;
  pn[4] = p1.x*inv_p; pn[5] = p1.y*inv_p; pn[6] = p1.z*inv_p; pn[7] = p1.w*inv_p;

  // sim0 against own fp8 row (consistent quantization with negatives)
  float dp = dot8_fp8(nenc[m * 64 + lane], pn);
  #pragma unroll
  for (int off = 1; off < 64; off <<= 1) dp += __shfl_xor(dp, off, 64);
  float s0 = dp * INV_TEMP;

  float sumexp = __expf(s0);
  float maxneg = -1e30f;

  for (int jj = 0; jj < NNEG; jj += 4) {
    int4 s4 = *((const int4*)&sel_lds[wave][jj]);  // wave-uniform broadcast
    int2 q0 = nenc[(size_t)s4.x * 64 + lane];
    int2 q1 = nenc[(size_t)s4.y * 64 + lane];
    int2 q2 = nenc[(size_t)s4.z * 64 + lane];
    int2 q3 = nenc[(size_t)s4.w * 64 + lane];
    float d0 = dot8_fp8(q0, pn);
    float d1 = dot8_fp8(q1, pn);
    float d2 = dot8_fp8(q2, pn);
    float d3 = dot8_fp8(q3, pn);
    #pragma unroll
    for (int off = 1; off < 64; off <<= 1) {  // 4 independent butterflies
      d0 += __shfl_xor(d0, off, 64);
      d1 += __shfl_xor(d1, off, 64);
      d2 += __shfl_xor(d2, off, 64);
      d3 += __shfl_xor(d3, off, 64);
    }
    float s_0 = d0 * INV_TEMP, s_1 = d1 * INV_TEMP;
    float s_2 = d2 * INV_TEMP, s_3 = d3 * INV_TEMP;
    maxneg = fmaxf(fmaxf(fmaxf(maxneg, s_0), fmaxf(s_1, s_2)), s_3);
    sumexp += __expf(s_0) + __expf(s_1) + __expf(s_2) + __expf(s_3);
  }

  if (lane == 0) {
    float lse = logf(sumexp);
    wred[wave] = make_float2(lse - s0, (s0 >= maxneg) ? 1.0f : 0.0f);
  }
  __syncthreads();
  if (threadIdx.x == 0) {
    float l = 0.0f, a = 0.0f;
    #pragma unroll
    for (int w = 0; w < 4; ++w) { l += wred[w].x; a += wred[w].y; }
    partials[blockIdx.x] = make_float2(l, a);
  }
}

// Kernel 3: reduce 1024 block partials -> (loss, acc)
__global__ __launch_bounds__(256) void k_finalize(
    const float2* __restrict__ partials, float* __restrict__ out) {
  int t = threadIdx.x;
  float l = 0.0f, a = 0.0f;
  #pragma unroll
  for (int i = 0; i < 4; ++i) {
    float2 v = partials[t + 256 * i];
    l += v.x; a += v.y;
  }
  #pragma unroll
  for (int off = 1; off < 64; off <<= 1) {
    l += __shfl_xor(l, off, 64);
    a += __shfl_xor(a, off, 64);
  }
  __shared__ float2 wred[4];
  if ((t & 63) == 0) wred[t >> 6] = make_float2(l, a);
  __syncthreads();
  if (t == 0) {
    out[0] = (wred[0].x + wred[1].x + wred[2].x + wred[3].x) * (1.0f / M_ROWS);
    out[1] = (wred[0].y + wred[1].y + wred[2].y + wred[3].y) * (1.0f / M_ROWS);
  }
}

extern "C" void kernel_launch(void* const* d_in, const int* in_sizes, int n_in,
                              void* d_out, int out_size, void* d_ws, size_t ws_size,
                              hipStream_t stream) {
  const float* pred = (const float*)d_in[0];
  const float* enc  = (const float*)d_in[1];
  const int*   ids  = (const int*)d_in[2];
  float* out = (float*)d_out;

  // ws: nenc fp8 table (2 MB) | partials (1024 float2)
  int2* nenc = (int2*)d_ws;
  float2* partials = (float2*)(nenc + (size_t)M_ROWS * 64);

  k_norm_enc<<<M_ROWS / 4, 256, 0, stream>>>(enc, ids, nenc);
  k_contrast<<<M_ROWS / 4, 256, 0, stream>>>(pred, ids, nenc, partials);
  k_finalize<<<1, 256, 0, stream>>>(partials, out);
}